// Round 3
// baseline (10447.366 us; speedup 1.0000x reference)
//
#include <hip/hip_runtime.h>

// Farthest Point Sampling: points (B, N, 3) fp32 -> indices (B, M) int32.
// B=16, N=65536, M=2048.  Reference semantics (locked earlier, absmax=0):
// float64 pipeline: dx=(double)x-(double)cx; d=((dx*dx+dy*dy)+dz*dz) with
// separate rounding (no FMA); min via fmin; argmax first-index tie-break.
//
// Transport: 4 self-tagged 8-B words per (parity, batch, rank) 64-B slot:
//   A = value_lo32<<32 | m<<16 | idx          (idx<65536: 16b)
//   B = value_hi32<<32 | m<<16 | idx
//   C = x_bits<<32     | m<<16 | y_hi16
//   D = y_lo16<<48     | z_bits<<16 | m
// Aligned 8-B stores are single-copy atomic; every word carries m, so any
// epoch-mix tear is detected and re-polled.  Reuse safety (parity m&1): a
// slot is rewritten at m+2 only after its writer finished reading all tags
// m+1, which post only after every block finished reading m.  0xAA poison
// tag = 0xAAAA != any m in [1,2048) => no init kernel.
//
// Round 8: XCD-local fast channel, hang-proof-by-construction (after two
// opaque failures with the inline-asm sc0 variant, suspected L1-stale spin):
//  * NO inline asm, NO getreg.  Fast reads use atomic CAS(0,0) at WORKGROUP
//    scope: vector atomics execute at the XCD L2 (L1 has no atomic path),
//    so they are architecturally immune to L1 staleness and never modify
//    memory (desired==expected).  Fast writes are workgroup-scope relaxed
//    stores: L1 is write-through, so they land in the local L2.
//  * Writer ALWAYS writes the agent (fabric) copy too — fire-and-forget, so
//    the proven channel is always available.
//  * Reader eligibility: 64-round probe of the fast slot at m==1 (after the
//    guaranteed agent read).  Fast polls are bounded (1024 rounds ~100 µs
//    vs <=3 µs legit skew); on timeout the lane permanently reverts to the
//    agent path.  Every failure mode degrades to the baseline exactly.
//  * Grid swizzle: batch = (lid&7) + 8*((lid>>3)&1), rank = lid>>4.  Under
//    round-robin dispatch (lid%8 == XCD) all 16 blocks of a batch share one
//    XCD (32 blocks/XCD = its 32 CUs) => polls are local-L2 (~300 cy RT)
//    instead of fabric (~700+ cy).  Placement is a speed heuristic only;
//    correctness never depends on it (Guideline 16).

#define N_PTS   65536
#define M_SAMP  2048
#define NT      512
#define BPB     16                  // blocks per batch
#define PTS_BLK (N_PTS / BPB)       // 4096
#define PPT     (PTS_BLK / NT)      // 8 points per thread
#define NWAVES  (NT / 64)           // 8
#define NBATCH  16
#define SLOT_U64 8                  // 64 B per slot
#define FAST_OFF (2 * NBATCH * BPB * SLOT_U64)   // 4096 u64 = 32 KB
#define PROBE_SPINS 64
#define FAST_SPINS  1024

typedef unsigned long long u64;

__device__ __forceinline__ u64 ld_agent(const u64* a) {
  return __hip_atomic_load(a, __ATOMIC_RELAXED, __HIP_MEMORY_SCOPE_AGENT);
}
__device__ __forceinline__ void st_agent(u64* a, u64 v) {
  __hip_atomic_store(a, v, __ATOMIC_RELAXED, __HIP_MEMORY_SCOPE_AGENT);
}
__device__ __forceinline__ void st_wg(u64* a, u64 v) {
  __hip_atomic_store(a, v, __ATOMIC_RELAXED, __HIP_MEMORY_SCOPE_WORKGROUP);
}
// L2-point read: CAS(0,0) never modifies memory (writes 0 only if the word
// is already 0) but executes at the XCD L2 and returns the current value.
__device__ __forceinline__ u64 ld_l2(u64* a) {
  u64 e = 0;
  __hip_atomic_compare_exchange_strong(a, &e, 0ull, __ATOMIC_RELAXED,
                                       __ATOMIC_RELAXED,
                                       __HIP_MEMORY_SCOPE_WORKGROUP);
  return e;
}

__global__ __launch_bounds__(NT, 2)
void fps_multi(const float* __restrict__ pts, int* __restrict__ out,
               u64* __restrict__ ws) {
  // Swizzle: batch b owns lids {(b&7) + 8*(2r + (b>>3)) : r=0..15} — all
  // congruent mod 8 => one XCD under round-robin dispatch.
  const int lid  = blockIdx.x;
  const int slot = lid >> 3;
  const int b    = (lid & 7) + ((slot & 1) << 3);   // batch
  const int rank = slot >> 1;                       // 0..BPB-1 within batch
  const float* __restrict__ p = pts + (size_t)b * (size_t)(N_PTS * 3);
  int* __restrict__ o = out + (size_t)b * M_SAMP;
  const int t = threadIdx.x;
  const int base = rank * PTS_BLK;

  __shared__ float  s_pts[PTS_BLK * 3];        // 48 KB slice
  __shared__ double s_bv[NWAVES];
  __shared__ int    s_bi[NWAVES];
  __shared__ float  s_c[3];                    // broadcast centroid coords

  for (int i = t; i < PTS_BLK * 3; i += NT)
    s_pts[i] = p[base * 3 + i];
  if (rank == 0 && t == 0) o[0] = 0;
  if (t == 0) { s_c[0] = p[0]; s_c[1] = p[1]; s_c[2] = p[2]; }  // seed pt 0
  __syncthreads();

  // Own points pre-converted to f64 in registers; (double)x is exact.
  double pd[PPT][3];
  double md[PPT];
#pragma unroll
  for (int j = 0; j < PPT; ++j) {
    const int l = t + j * NT;
    pd[j][0] = (double)s_pts[3 * l + 0];
    pd[j][1] = (double)s_pts[3 * l + 1];
    pd[j][2] = (double)s_pts[3 * l + 2];
    md[j] = 1e10;
  }

  bool fast = false;   // per reader lane (t<BPB): fast channel verified

  for (int m = 1; m < M_SAMP; ++m) {
    const double cx = (double)s_c[0];
    const double cy = (double)s_c[1];
    const double cz = (double)s_c[2];

    double bestv = -1.0;    // distances >= 0 always beat this
    int    besti = 0;

    // Indices base + t + j*NT ascend with j => strict '>' keeps the first
    // (lowest-index) maximum within a thread.
#pragma unroll
    for (int j = 0; j < PPT; ++j) {
      const double dx = __dsub_rn(pd[j][0], cx);
      const double dy = __dsub_rn(pd[j][1], cy);
      const double dz = __dsub_rn(pd[j][2], cz);
      const double d  = __dadd_rn(__dadd_rn(__dmul_rn(dx, dx),
                                            __dmul_rn(dy, dy)),
                                  __dmul_rn(dz, dz));
      const double nmd = fmin(md[j], d);
      md[j] = nmd;
      if (nmd > bestv) { bestv = nmd; besti = base + t + j * NT; }
    }

    // 64-lane butterfly argmax, min-index tie-break.
#pragma unroll
    for (int off = 32; off >= 1; off >>= 1) {
      const double ov = __shfl_xor(bestv, off, 64);
      const int    oi = __shfl_xor(besti, off, 64);
      if (ov > bestv || (ov == bestv && oi < besti)) { bestv = ov; besti = oi; }
    }
    if ((t & 63) == 0) { s_bv[t >> 6] = bestv; s_bi[t >> 6] = besti; }
    __syncthreads();

    // Wave 0: finish block reduction, publish, poll, cross-block reduce.
    if (t < 64) {
      if (t < NWAVES) {
        bestv = s_bv[t]; besti = s_bi[t];
#pragma unroll
        for (int off = NWAVES / 2; off >= 1; off >>= 1) {
          const double ov = __shfl_xor(bestv, off, 64);
          const int    oi = __shfl_xor(besti, off, 64);
          if (ov > bestv || (ov == bestv && oi < besti)) { bestv = ov; besti = oi; }
        }
      }
      const u64 mm = (u64)(unsigned)m;
      const int pb = ((m & 1) * NBATCH + b) * BPB;
      if (t == 0) {
        const int l = besti - base;           // block winner is in our slice
        const unsigned xb = __float_as_uint(s_pts[3 * l + 0]);
        const unsigned yb = __float_as_uint(s_pts[3 * l + 1]);
        const unsigned zb = __float_as_uint(s_pts[3 * l + 2]);
        const u64 vb = (u64)__double_as_longlong(bestv);
        const u64 ti = (mm << 16) | (u64)(unsigned)besti;
        const u64 Aw = (vb << 32) | ti;
        const u64 Bw = (vb & 0xFFFFFFFF00000000ull) | ti;
        const u64 Cw = ((u64)xb << 32) | (mm << 16) | (u64)(yb >> 16);
        const u64 Dw = ((u64)(yb & 0xFFFFu) << 48) | ((u64)zb << 16) | mm;
        // Fast (local-L2) copy first, then the always-available agent copy.
        u64* fs = ws + FAST_OFF + (size_t)(pb + rank) * SLOT_U64;
        st_wg(fs + 0, Aw);
        st_wg(fs + 1, Bw);
        st_wg(fs + 2, Cw);
        st_wg(fs + 3, Dw);
        u64* s = ws + (size_t)(pb + rank) * SLOT_U64;
        st_agent(&s[0], Aw);
        st_agent(&s[1], Bw);
        st_agent(&s[2], Cw);
        st_agent(&s[3], Dw);
      }
      if (t < BPB) {
        u64 A, B, C, D;
        bool got = false;
        u64* fs = ws + FAST_OFF + (size_t)(pb + t) * SLOT_U64;
        if (fast) {
          for (int sp = 0; sp < FAST_SPINS; ++sp) {
            A = ld_l2(fs + 0);
            B = ld_l2(fs + 1);
            C = ld_l2(fs + 2);
            D = ld_l2(fs + 3);
            const bool ok = (((A >> 16) & 0xFFFFull) == mm) &
                            (((B >> 16) & 0xFFFFull) == mm) &
                            (((C >> 16) & 0xFFFFull) == mm) &
                            ((D & 0xFFFFull) == mm);
            if (ok) { got = true; break; }
          }
          if (!got) fast = false;   // permanent revert; agent always written
        }
        if (!got) {
          const u64* rs = ws + (size_t)(pb + t) * SLOT_U64;
          for (;;) {
            A = ld_agent(rs + 0);
            B = ld_agent(rs + 1);
            C = ld_agent(rs + 2);
            D = ld_agent(rs + 3);
            const bool ok = (((A >> 16) & 0xFFFFull) == mm) &
                            (((B >> 16) & 0xFFFFull) == mm) &
                            (((C >> 16) & 0xFFFFull) == mm) &
                            ((D & 0xFFFFull) == mm);
            if (ok) break;
          }
          if (m == 1) {
            // One-shot bounded probe: enable fast only if the writer's
            // local-L2 store is actually visible through my L2.
            for (int sp = 0; sp < PROBE_SPINS && !fast; ++sp) {
              const u64 a2 = ld_l2(fs + 0);
              const u64 b2 = ld_l2(fs + 1);
              const u64 c2 = ld_l2(fs + 2);
              const u64 d2 = ld_l2(fs + 3);
              fast = (((a2 >> 16) & 0xFFFFull) == mm) &
                     (((b2 >> 16) & 0xFFFFull) == mm) &
                     (((c2 >> 16) & 0xFFFFull) == mm) &
                     ((d2 & 0xFFFFull) == mm);
            }
          }
        }
        double v = __longlong_as_double(
            (long long)((B & 0xFFFFFFFF00000000ull) | (A >> 32)));
        int   i = (int)(A & 0xFFFFull);
        float fx = __uint_as_float((unsigned)(C >> 32));
        float fy = __uint_as_float((unsigned)(((C & 0xFFFFull) << 16) | (D >> 48)));
        float fz = __uint_as_float((unsigned)((D >> 16) & 0xFFFFFFFFull));
        int r = t;                              // contributing rank
#pragma unroll
        for (int off = BPB / 2; off >= 1; off >>= 1) {
          const double ov = __shfl_xor(v, off, 64);
          const int    oi = __shfl_xor(i, off, 64);
          const int    orr = __shfl_xor(r, off, 64);
          if (ov > v || (ov == v && oi < i)) { v = ov; i = oi; r = orr; }
        }
        // Lanes 0..15 agree on winner rank r; pull its coords by shuffle.
        fx = __shfl(fx, r, 64);
        fy = __shfl(fy, r, 64);
        fz = __shfl(fz, r, 64);
        if (t == 0) {
          s_c[0] = fx; s_c[1] = fy; s_c[2] = fz;
          if (rank == 0) o[m] = i;
        }
      }
    }
    __syncthreads();
  }
}

extern "C" void kernel_launch(void* const* d_in, const int* in_sizes, int n_in,
                              void* d_out, int out_size, void* d_ws, size_t ws_size,
                              hipStream_t stream) {
  const float* pts = (const float*)d_in[0];
  int* out = (int*)d_out;
  const int B = in_sizes[0] / (N_PTS * 3);   // 16
  // ws usage: agent region 32 KB + fast (local-L2) region 32 KB = 64 KB,
  // identical total footprint to the proven baseline.
  hipLaunchKernelGGL(fps_multi, dim3(BPB * B), dim3(NT), 0, stream,
                     pts, out, (u64*)d_ws);
}

// Round 4
// 9167.885 us; speedup vs baseline: 1.1396x; 1.1396x over previous
//
#include <hip/hip_runtime.h>

// Farthest Point Sampling: points (B, N, 3) fp32 -> indices (B, M) int32.
// B=16, N=65536, M=2048.  Reference semantics (locked earlier, absmax=0):
// float64 pipeline: dx=(double)x-(double)cx; d=((dx*dx+dy*dy)+dz*dz) with
// separate rounding (no FMA); min via fmin; argmax first-index tie-break.
//
// Transport: 4 self-tagged 8-B words per (parity, batch, rank) 64-B slot:
//   A = value_lo32<<32 | m<<16 | idx          (idx<65536: 16b)
//   B = value_hi32<<32 | m<<16 | idx
//   C = x_bits<<32     | m<<16 | y_hi16
//   D = y_lo16<<48     | z_bits<<16 | m
// Aligned 8-B stores are single-copy atomic; every word carries m, so any
// epoch-mix tear is detected and re-polled.  Reuse safety (parity m&1): a
// slot is rewritten at m+2 only after its writer finished reading all tags
// m+1, which post only after every block finished reading m.  0xAA poison
// tag = 0xAAAA != any m in [1,2048) => no init kernel.
//
// Round 9: R3 proved the XCD-local channel works (swizzle co-locates the
// batch; st_wg lands in local L2; CAS sees it: FETCH 277->6 MB) but the
// poll instrument was wrong: 16 lanes x 4 CAS to the SAME 64-B line per
// round => L2 serializes 64 RMWs (~2k cy/round), delays the writer's store
// to that line (feedback -> 176 rounds avg, WRITE_SIZE 2.95 GB, 41 ms
// outliers).  Fix, keeping the proven structure:
//  * Poll ONLY word A (1 CAS/lane/round, 16 distinct words) + s_sleep(1)
//    backoff; after A hits, CAS-read B,C,D (written together with A; tags
//    catch skew; plain loads would see stale L1 - that killed R1/R2).
//  * Hard caps + PERMANENT demotion to the agent path (R3's flaw: a slow
//    fast path that never times out).  Worst case = baseline + ~7 us.
//  * Writer always writes both channels; agent path byte-identical to the
//    5839 us baseline.  Correctness never depends on placement (G16).

#define N_PTS   65536
#define M_SAMP  2048
#define NT      512
#define BPB     16                  // blocks per batch
#define PTS_BLK (N_PTS / BPB)       // 4096
#define PPT     (PTS_BLK / NT)      // 8 points per thread
#define NWAVES  (NT / 64)           // 8
#define NBATCH  16
#define SLOT_U64 8                  // 64 B per slot
#define FAST_OFF (2 * NBATCH * BPB * SLOT_U64)   // 4096 u64 = 32 KB
#define PROBE_SPINS 64
#define A_SPINS     48
#define BCD_SPINS   16

typedef unsigned long long u64;

__device__ __forceinline__ u64 ld_agent(const u64* a) {
  return __hip_atomic_load(a, __ATOMIC_RELAXED, __HIP_MEMORY_SCOPE_AGENT);
}
__device__ __forceinline__ void st_agent(u64* a, u64 v) {
  __hip_atomic_store(a, v, __ATOMIC_RELAXED, __HIP_MEMORY_SCOPE_AGENT);
}
__device__ __forceinline__ void st_wg(u64* a, u64 v) {
  __hip_atomic_store(a, v, __ATOMIC_RELAXED, __HIP_MEMORY_SCOPE_WORKGROUP);
}
// L2-point read: CAS(0,0) never modifies memory (writes 0 only if the word
// is already 0) but executes at the XCD L2 (atomics bypass L1) and returns
// the current value.  This is the ONLY proven L1-immune cross-CU read on
// this chip from our experiments; plain/sc0 loads spin on stale L1.
__device__ __forceinline__ u64 ld_l2(u64* a) {
  u64 e = 0;
  __hip_atomic_compare_exchange_strong(a, &e, 0ull, __ATOMIC_RELAXED,
                                       __ATOMIC_RELAXED,
                                       __HIP_MEMORY_SCOPE_WORKGROUP);
  return e;
}

__global__ __launch_bounds__(NT, 2)
void fps_multi(const float* __restrict__ pts, int* __restrict__ out,
               u64* __restrict__ ws) {
  // Swizzle: batch b owns lids {(b&7) + 8*(2r + (b>>3)) : r=0..15} — all
  // congruent mod 8 => one XCD under round-robin dispatch.
  const int lid  = blockIdx.x;
  const int slot = lid >> 3;
  const int b    = (lid & 7) + ((slot & 1) << 3);   // batch
  const int rank = slot >> 1;                       // 0..BPB-1 within batch
  const float* __restrict__ p = pts + (size_t)b * (size_t)(N_PTS * 3);
  int* __restrict__ o = out + (size_t)b * M_SAMP;
  const int t = threadIdx.x;
  const int base = rank * PTS_BLK;

  __shared__ float  s_pts[PTS_BLK * 3];        // 48 KB slice
  __shared__ double s_bv[NWAVES];
  __shared__ int    s_bi[NWAVES];
  __shared__ float  s_c[3];                    // broadcast centroid coords

  for (int i = t; i < PTS_BLK * 3; i += NT)
    s_pts[i] = p[base * 3 + i];
  if (rank == 0 && t == 0) o[0] = 0;
  if (t == 0) { s_c[0] = p[0]; s_c[1] = p[1]; s_c[2] = p[2]; }  // seed pt 0
  __syncthreads();

  // Own points pre-converted to f64 in registers; (double)x is exact.
  double pd[PPT][3];
  double md[PPT];
#pragma unroll
  for (int j = 0; j < PPT; ++j) {
    const int l = t + j * NT;
    pd[j][0] = (double)s_pts[3 * l + 0];
    pd[j][1] = (double)s_pts[3 * l + 1];
    pd[j][2] = (double)s_pts[3 * l + 2];
    md[j] = 1e10;
  }

  bool fast = false;   // per reader lane (t<BPB): fast channel verified

  for (int m = 1; m < M_SAMP; ++m) {
    const double cx = (double)s_c[0];
    const double cy = (double)s_c[1];
    const double cz = (double)s_c[2];

    double bestv = -1.0;    // distances >= 0 always beat this
    int    besti = 0;

    // Indices base + t + j*NT ascend with j => strict '>' keeps the first
    // (lowest-index) maximum within a thread.
#pragma unroll
    for (int j = 0; j < PPT; ++j) {
      const double dx = __dsub_rn(pd[j][0], cx);
      const double dy = __dsub_rn(pd[j][1], cy);
      const double dz = __dsub_rn(pd[j][2], cz);
      const double d  = __dadd_rn(__dadd_rn(__dmul_rn(dx, dx),
                                            __dmul_rn(dy, dy)),
                                  __dmul_rn(dz, dz));
      const double nmd = fmin(md[j], d);
      md[j] = nmd;
      if (nmd > bestv) { bestv = nmd; besti = base + t + j * NT; }
    }

    // 64-lane butterfly argmax, min-index tie-break.
#pragma unroll
    for (int off = 32; off >= 1; off >>= 1) {
      const double ov = __shfl_xor(bestv, off, 64);
      const int    oi = __shfl_xor(besti, off, 64);
      if (ov > bestv || (ov == bestv && oi < besti)) { bestv = ov; besti = oi; }
    }
    if ((t & 63) == 0) { s_bv[t >> 6] = bestv; s_bi[t >> 6] = besti; }
    __syncthreads();

    // Wave 0: finish block reduction, publish, poll, cross-block reduce.
    if (t < 64) {
      if (t < NWAVES) {
        bestv = s_bv[t]; besti = s_bi[t];
#pragma unroll
        for (int off = NWAVES / 2; off >= 1; off >>= 1) {
          const double ov = __shfl_xor(bestv, off, 64);
          const int    oi = __shfl_xor(besti, off, 64);
          if (ov > bestv || (ov == bestv && oi < besti)) { bestv = ov; besti = oi; }
        }
      }
      const u64 mm = (u64)(unsigned)m;
      const int pb = ((m & 1) * NBATCH + b) * BPB;
      if (t == 0) {
        const int l = besti - base;           // block winner is in our slice
        const unsigned xb = __float_as_uint(s_pts[3 * l + 0]);
        const unsigned yb = __float_as_uint(s_pts[3 * l + 1]);
        const unsigned zb = __float_as_uint(s_pts[3 * l + 2]);
        const u64 vb = (u64)__double_as_longlong(bestv);
        const u64 ti = (mm << 16) | (u64)(unsigned)besti;
        const u64 Aw = (vb << 32) | ti;
        const u64 Bw = (vb & 0xFFFFFFFF00000000ull) | ti;
        const u64 Cw = ((u64)xb << 32) | (mm << 16) | (u64)(yb >> 16);
        const u64 Dw = ((u64)(yb & 0xFFFFu) << 48) | ((u64)zb << 16) | mm;
        // Fast (local-L2) copy first, then the always-available agent copy.
        u64* fs = ws + FAST_OFF + (size_t)(pb + rank) * SLOT_U64;
        st_wg(fs + 0, Aw);
        st_wg(fs + 1, Bw);
        st_wg(fs + 2, Cw);
        st_wg(fs + 3, Dw);
        u64* s = ws + (size_t)(pb + rank) * SLOT_U64;
        st_agent(&s[0], Aw);
        st_agent(&s[1], Bw);
        st_agent(&s[2], Cw);
        st_agent(&s[3], Dw);
      }
      if (t < BPB) {
        u64 A, B, C, D;
        bool got = false;
        u64* fs = ws + FAST_OFF + (size_t)(pb + t) * SLOT_U64;
        if (fast) {
          // Phase 1: poll ONLY word A — one CAS per round, 16 distinct
          // words across the wave, backoff between misses.
          bool gotA = false;
          for (int sp = 0; sp < A_SPINS; ++sp) {
            A = ld_l2(fs + 0);
            if (((A >> 16) & 0xFFFFull) == mm) { gotA = true; break; }
            __builtin_amdgcn_s_sleep(1);
          }
          if (gotA) {
            // Phase 2: B,C,D were stored together with A; typically 1 round.
            for (int sp = 0; sp < BCD_SPINS; ++sp) {
              B = ld_l2(fs + 1);
              C = ld_l2(fs + 2);
              D = ld_l2(fs + 3);
              const bool ok = (((B >> 16) & 0xFFFFull) == mm) &
                              (((C >> 16) & 0xFFFFull) == mm) &
                              ((D & 0xFFFFull) == mm);
              if (ok) { got = true; break; }
              __builtin_amdgcn_s_sleep(1);
            }
          }
          if (!got) fast = false;   // permanent demotion; agent always written
        }
        if (!got) {
          const u64* rs = ws + (size_t)(pb + t) * SLOT_U64;
          for (;;) {
            A = ld_agent(rs + 0);
            B = ld_agent(rs + 1);
            C = ld_agent(rs + 2);
            D = ld_agent(rs + 3);
            const bool ok = (((A >> 16) & 0xFFFFull) == mm) &
                            (((B >> 16) & 0xFFFFull) == mm) &
                            (((C >> 16) & 0xFFFFull) == mm) &
                            ((D & 0xFFFFull) == mm);
            if (ok) break;
          }
          if (m == 1) {
            // One-shot bounded probe: enable fast only if the writer's
            // local-L2 stores are actually visible through my L2.
            for (int sp = 0; sp < PROBE_SPINS && !fast; ++sp) {
              const u64 a2 = ld_l2(fs + 0);
              const u64 b2 = ld_l2(fs + 1);
              const u64 c2 = ld_l2(fs + 2);
              const u64 d2 = ld_l2(fs + 3);
              fast = (((a2 >> 16) & 0xFFFFull) == mm) &
                     (((b2 >> 16) & 0xFFFFull) == mm) &
                     (((c2 >> 16) & 0xFFFFull) == mm) &
                     ((d2 & 0xFFFFull) == mm);
              if (!fast) __builtin_amdgcn_s_sleep(1);
            }
          }
        }
        double v = __longlong_as_double(
            (long long)((B & 0xFFFFFFFF00000000ull) | (A >> 32)));
        int   i = (int)(A & 0xFFFFull);
        float fx = __uint_as_float((unsigned)(C >> 32));
        float fy = __uint_as_float((unsigned)(((C & 0xFFFFull) << 16) | (D >> 48)));
        float fz = __uint_as_float((unsigned)((D >> 16) & 0xFFFFFFFFull));
        int r = t;                              // contributing rank
#pragma unroll
        for (int off = BPB / 2; off >= 1; off >>= 1) {
          const double ov = __shfl_xor(v, off, 64);
          const int    oi = __shfl_xor(i, off, 64);
          const int    orr = __shfl_xor(r, off, 64);
          if (ov > v || (ov == v && oi < i)) { v = ov; i = oi; r = orr; }
        }
        // Lanes 0..15 agree on winner rank r; pull its coords by shuffle.
        fx = __shfl(fx, r, 64);
        fy = __shfl(fy, r, 64);
        fz = __shfl(fz, r, 64);
        if (t == 0) {
          s_c[0] = fx; s_c[1] = fy; s_c[2] = fz;
          if (rank == 0) o[m] = i;
        }
      }
    }
    __syncthreads();
  }
}

extern "C" void kernel_launch(void* const* d_in, const int* in_sizes, int n_in,
                              void* d_out, int out_size, void* d_ws, size_t ws_size,
                              hipStream_t stream) {
  const float* pts = (const float*)d_in[0];
  int* out = (int*)d_out;
  const int B = in_sizes[0] / (N_PTS * 3);   // 16
  // ws usage: agent region 32 KB + fast (local-L2) region 32 KB = 64 KB,
  // identical total footprint to the proven baseline.
  hipLaunchKernelGGL(fps_multi, dim3(BPB * B), dim3(NT), 0, stream,
                     pts, out, (u64*)d_ws);
}